// Round 5
// baseline (74.403 us; speedup 1.0000x reference)
//
#include <hip/hip_runtime.h>

#define IMG_H 1024
#define IMG_W 1024
#define IMG_C 3

// Interior: x in [2,1017], 8 px per thread, 127 strips per row.
#define SPR 127
// Boundary: frame rows 0,1,1021-1023; cols {0,1} and {1018..1023} for y in [2,1020].
#define INT_ROWS 1019
#define BND_PER_C (5 * 1024 + INT_ROWS * 8)    // 13,272
#define N_BND (IMG_C * BND_PER_C)              // 39,816
#define NB_BND ((N_BND + 255) / 256)           // 156

__device__ __forceinline__ float med3f(float a, float b, float c) {
    return __builtin_amdgcn_fmed3f(a, b, c);
}

// sort5 via sort3 + two med3-insertions: 12 VALU ops (v_min3/v_med3/v_max3).
// Hand-verified: [5,1,4,2,3] -> sort3(5,1,4)=(1,4,5); ins2 -> (1,2,4,5); ins3 -> (1,2,3,4,5).
__device__ __forceinline__ void sort5(float* a) {
    float l0 = fminf(fminf(a[0], a[1]), a[2]);   // v_min3
    float l2 = fmaxf(fmaxf(a[0], a[1]), a[2]);   // v_max3
    float l1 = med3f(a[0], a[1], a[2]);
    float x = a[3];
    float t0 = fminf(x, l0);
    float t1 = med3f(x, l0, l1);
    float t2 = med3f(x, l1, l2);
    float t3 = fmaxf(x, l2);
    float z = a[4];
    a[0] = fminf(z, t0);
    a[1] = med3f(z, t0, t1);
    a[2] = med3f(z, t1, t2);
    a[3] = med3f(z, t2, t3);
    a[4] = fmaxf(z, t3);
}

// Batcher odd-even merges (verified rounds 2-4, absmax 0).
__device__ __forceinline__ void merge22(const float* A, const float* B, float* out) {
    float e0 = fminf(A[0], B[0]), e1 = fmaxf(A[0], B[0]);
    float o0 = fminf(A[1], B[1]), o1 = fmaxf(A[1], B[1]);
    out[0] = e0;
    out[1] = fminf(o0, e1); out[2] = fmaxf(o0, e1);
    out[3] = o1;
}

__device__ __forceinline__ void merge33(const float* A, const float* B, float* out) {
    float Ae[2] = {A[0], A[2]}, Be[2] = {B[0], B[2]};
    float E[4];
    merge22(Ae, Be, E);
    float O0 = fminf(A[1], B[1]), O1 = fmaxf(A[1], B[1]);
    out[0] = E[0];
    out[1] = fminf(O0, E[1]); out[2] = fmaxf(O0, E[1]);
    out[3] = fminf(O1, E[2]); out[4] = fmaxf(O1, E[2]);
    out[5] = E[3];
}

__device__ __forceinline__ void merge55(const float* A, const float* B, float* out) {
    float Ae[3] = {A[0], A[2], A[4]}, Be[3] = {B[0], B[2], B[4]};
    float E[6];
    merge33(Ae, Be, E);
    float Ao[2] = {A[1], A[3]}, Bo[2] = {B[1], B[3]};
    float O[4];
    merge22(Ao, Bo, O);
    out[0] = E[0];
    out[1] = fminf(O[0], E[1]); out[2] = fmaxf(O[0], E[1]);
    out[3] = fminf(O[1], E[2]); out[4] = fmaxf(O[1], E[2]);
    out[5] = fminf(O[2], E[3]); out[6] = fmaxf(O[2], E[3]);
    out[7] = fminf(O[3], E[4]); out[8] = fmaxf(O[3], E[4]);
    out[9] = E[5];
}

// merge of two sorted-10s, only outputs 7..12 kept (rest DCE'd).
__device__ __forceinline__ void merge1010_mid(const float* A, const float* B, float* mid) {
    float Ae[5] = {A[0], A[2], A[4], A[6], A[8]}, Be[5] = {B[0], B[2], B[4], B[6], B[8]};
    float E[10];
    merge55(Ae, Be, E);
    float Ao[5] = {A[1], A[3], A[5], A[7], A[9]}, Bo[5] = {B[1], B[3], B[5], B[7], B[9]};
    float O[10];
    merge55(Ao, Bo, O);
    mid[0] = fminf(O[3], E[4]); mid[1] = fmaxf(O[3], E[4]);
    mid[2] = fminf(O[4], E[5]); mid[3] = fmaxf(O[4], E[5]);
    mid[4] = fminf(O[5], E[6]); mid[5] = fmaxf(O[5], E[6]);
}

// median(25) = rank-5 (0-idx) of mid6 (sorted) ∪ sorted col5 (verified rounds 2-4).
__device__ __forceinline__ float final_median(const float* mid, const float* c5) {
    const float INF = __builtin_inff();
    float Ae[3] = {mid[0], mid[2], mid[4]}, Be[3] = {c5[0], c5[2], c5[4]};
    float E[6];
    merge33(Ae, Be, E);
    float Ao[3] = {mid[1], mid[3], mid[5]}, Bo[3] = {c5[1], c5[3], INF};
    float O[6];
    merge33(Ao, Bo, O);
    return fminf(O[2], E[3]);
}

// ===================== interior: block (128,2), grid (1, 510, 3) ==============
__global__ __launch_bounds__(256, 3) void median5_interior(const float* __restrict__ img,
                                                           float* __restrict__ out) {
    int xs = threadIdx.x;                       // 0..127
    int y = 2 + 2 * blockIdx.y + threadIdx.y;   // 2..1021
    int c = blockIdx.z;
    if (xs >= SPR || y > 1020) return;
    int x0 = 2 + 8 * xs;

    const float* p = img + (size_t)c * IMG_H * IMG_W;

    // 12 columns (abs x0-2 .. x0+9) x 5 rows; x0-2 = 8*xs -> 32B aligned.
    float col[12][5];
#pragma unroll
    for (int r = 0; r < 5; ++r) {
        const float4* rp = (const float4*)(p + (y - 2 + r) * IMG_W + (x0 - 2));
        float4 a = rp[0];
        float4 b = rp[1];
        float4 d = rp[2];
        col[0][r] = a.x; col[1][r] = a.y; col[2][r]  = a.z; col[3][r]  = a.w;
        col[4][r] = b.x; col[5][r] = b.y; col[6][r]  = b.z; col[7][r]  = b.w;
        col[8][r] = d.x; col[9][r] = d.y; col[10][r] = d.z; col[11][r] = d.w;
    }
#pragma unroll
    for (int j = 0; j < 12; ++j) sort5(col[j]);

    float M0[10], M1[10], M2[10], M3[10], M4[10], M5[10];
    merge55(col[0], col[1], M0);
    merge55(col[2], col[3], M1);
    merge55(col[4], col[5], M2);
    merge55(col[6], col[7], M3);
    merge55(col[8], col[9], M4);
    merge55(col[10], col[11], M5);

    float mid[6];
    float r0, r1, r2, r3, r4, r5, r6, r7;
    merge1010_mid(M0, M1, mid);
    r0 = final_median(mid, col[4]);
    merge1010_mid(M1, M2, mid);
    r1 = final_median(mid, col[1]);
    r2 = final_median(mid, col[6]);
    merge1010_mid(M2, M3, mid);
    r3 = final_median(mid, col[3]);
    r4 = final_median(mid, col[8]);
    merge1010_mid(M3, M4, mid);
    r5 = final_median(mid, col[5]);
    r6 = final_median(mid, col[10]);
    merge1010_mid(M4, M5, mid);
    r7 = final_median(mid, col[7]);

    float* po = out + (size_t)c * IMG_H * IMG_W + (size_t)y * IMG_W + x0;
    float2* po2 = (float2*)po;                  // 8B aligned
    po2[0] = make_float2(r0, r1);
    po2[1] = make_float2(r2, r3);
    po2[2] = make_float2(r4, r5);
    po2[3] = make_float2(r6, r7);
}

// ===================== boundary frame: verified bitonic-32 ====================
__global__ __launch_bounds__(256) void median5_boundary(const float* __restrict__ img,
                                                        float* __restrict__ out) {
    const float INF = __builtin_inff();
    int gid = blockIdx.x * 256 + threadIdx.x;
    if (gid >= N_BND) return;
    int c = gid / BND_PER_C;
    int b = gid % BND_PER_C;
    int y, x;
    if (b < 2048) {                 // rows 0,1
        y = b >> 10; x = b & 1023;
    } else if (b < 5120) {          // rows 1021..1023
        int t2 = b - 2048;
        y = 1021 + (t2 >> 10); x = t2 & 1023;
    } else {                        // rows 2..1020, cols {0,1} ∪ {1018..1023}
        int t2 = b - 5120;
        y = 2 + (t2 >> 3);
        int m = t2 & 7;
        x = (m < 2) ? m : (1016 + m);
    }

    const float* p = img + (size_t)c * IMG_H * IMG_W;
    float v[32];
#pragma unroll
    for (int i = 25; i < 32; ++i) v[i] = INF;
#pragma unroll
    for (int dy = -2; dy <= 2; ++dy) {
#pragma unroll
        for (int dx = -2; dx <= 2; ++dx) {
            int yy = y + dy;
            int xx = x + dx;
            bool valid = (yy >= 0) && (yy <= IMG_H - 2) && (xx >= 0) && (xx <= IMG_W - 2);
            int yc = min(max(yy, 0), IMG_H - 1);
            int xc = min(max(xx, 0), IMG_W - 1);
            float val = p[yc * IMG_W + xc];
            v[(dy + 2) * 5 + (dx + 2)] = valid ? val : INF;
        }
    }
#pragma unroll
    for (int k = 2; k <= 32; k <<= 1) {
#pragma unroll
        for (int j = k >> 1; j > 0; j >>= 1) {
#pragma unroll
            for (int i = 0; i < 32; ++i) {
                int l = i ^ j;
                if (l > i) {
                    bool up = ((i & k) == 0);
                    float a = v[i];
                    float b2 = v[l];
                    float mn = fminf(a, b2);
                    float mx = fmaxf(a, b2);
                    v[i] = up ? mn : mx;
                    v[l] = up ? mx : mn;
                }
            }
        }
    }
    int ny = min(y + 2, IMG_H - 2) - max(y - 2, 0) + 1;
    int nx = min(x + 2, IMG_W - 2) - max(x - 2, 0) + 1;
    int n = ny * nx;
    int ilo = (n - 1) >> 1;
    int ihi = n >> 1;
    float lo = 0.0f, hi = 0.0f;
#pragma unroll
    for (int i = 0; i < 13; ++i) {
        if (i == ilo) lo = v[i];
        if (i == ihi) hi = v[i];
    }
    out[(size_t)c * IMG_H * IMG_W + (size_t)y * IMG_W + x] = 0.5f * (lo + hi);
}

extern "C" void kernel_launch(void* const* d_in, const int* in_sizes, int n_in,
                              void* d_out, int out_size, void* d_ws, size_t ws_size,
                              hipStream_t stream) {
    const float* img = (const float*)d_in[0];
    float* out = (float*)d_out;
    dim3 iblock(128, 2, 1);
    dim3 igrid(1, 510, IMG_C);
    median5_interior<<<igrid, iblock, 0, stream>>>(img, out);
    median5_boundary<<<NB_BND, 256, 0, stream>>>(img, out);
}

// Round 6
// 70.127 us; speedup vs baseline: 1.0610x; 1.0610x over previous
//
#include <hip/hip_runtime.h>

#define IMG_H 1024
#define IMG_W 1024
#define IMG_C 3

// Interior: x in [2,1017], 8 px per thread, 127 strips per row.
#define SPR 127
#define INT_ROWS 1019                          // y = 2..1020
#define N_STRIPS (IMG_C * INT_ROWS * SPR)      // 388,239
#define NB_INT ((N_STRIPS + 255) / 256)        // 1517
#define BND_PER_C (5 * 1024 + INT_ROWS * 8)    // 13,272
#define N_BND (IMG_C * BND_PER_C)              // 39,816
#define NB_BND ((N_BND + 255) / 256)           // 156

// ===== packed f16x2 compare-exchange machinery =====
typedef _Float16 h2 __attribute__((ext_vector_type(2)));

__device__ __forceinline__ h2 h2min(h2 a, h2 b) { return __builtin_elementwise_min(a, b); }
__device__ __forceinline__ h2 h2max(h2 a, h2 b) { return __builtin_elementwise_max(a, b); }
__device__ __forceinline__ void CEh(h2& a, h2& b) { h2 t = h2min(a, b); b = h2max(a, b); a = t; }

__device__ __forceinline__ h2 pkrtz(float a, float b) {
    auto v = __builtin_amdgcn_cvt_pkrtz(a, b);   // v_cvt_pkrtz_f16_f32: {a,b} -> f16x2
    h2 r;
    __builtin_memcpy(&r, &v, sizeof(r));
    return r;
}

// 9-CE optimal sorting network for 5 (verified by exhaustive 0-1 principle).
__device__ __forceinline__ void sort5h(h2* a) {
    CEh(a[0], a[1]); CEh(a[3], a[4]); CEh(a[2], a[4]); CEh(a[2], a[3]);
    CEh(a[0], a[3]); CEh(a[0], a[2]); CEh(a[1], a[4]); CEh(a[1], a[3]);
    CEh(a[1], a[2]);
}

// Batcher odd-even merges, packed (same networks verified rounds 2-5 in f32).
__device__ __forceinline__ void merge22h(const h2* A, const h2* B, h2* out) {
    h2 e0 = h2min(A[0], B[0]), e1 = h2max(A[0], B[0]);
    h2 o0 = h2min(A[1], B[1]), o1 = h2max(A[1], B[1]);
    out[0] = e0;
    out[1] = h2min(o0, e1); out[2] = h2max(o0, e1);
    out[3] = o1;
}

__device__ __forceinline__ void merge33h(const h2* A, const h2* B, h2* out) {
    h2 Ae[2] = {A[0], A[2]}, Be[2] = {B[0], B[2]};
    h2 E[4];
    merge22h(Ae, Be, E);
    h2 O0 = h2min(A[1], B[1]), O1 = h2max(A[1], B[1]);
    out[0] = E[0];
    out[1] = h2min(O0, E[1]); out[2] = h2max(O0, E[1]);
    out[3] = h2min(O1, E[2]); out[4] = h2max(O1, E[2]);
    out[5] = E[3];
}

__device__ __forceinline__ void merge55h(const h2* A, const h2* B, h2* out) {
    h2 Ae[3] = {A[0], A[2], A[4]}, Be[3] = {B[0], B[2], B[4]};
    h2 E[6];
    merge33h(Ae, Be, E);
    h2 Ao[2] = {A[1], A[3]}, Bo[2] = {B[1], B[3]};
    h2 O[4];
    merge22h(Ao, Bo, O);
    out[0] = E[0];
    out[1] = h2min(O[0], E[1]); out[2] = h2max(O[0], E[1]);
    out[3] = h2min(O[1], E[2]); out[4] = h2max(O[1], E[2]);
    out[5] = h2min(O[2], E[3]); out[6] = h2max(O[2], E[3]);
    out[7] = h2min(O[3], E[4]); out[8] = h2max(O[3], E[4]);
    out[9] = E[5];
}

// merge of two sorted-10s, only outputs 7..12 kept (rest DCE'd).
__device__ __forceinline__ void merge1010_midh(const h2* A, const h2* B, h2* mid) {
    h2 Ae[5] = {A[0], A[2], A[4], A[6], A[8]}, Be[5] = {B[0], B[2], B[4], B[6], B[8]};
    h2 E[10];
    merge55h(Ae, Be, E);
    h2 Ao[5] = {A[1], A[3], A[5], A[7], A[9]}, Bo[5] = {B[1], B[3], B[5], B[7], B[9]};
    h2 O[10];
    merge55h(Ao, Bo, O);
    mid[0] = h2min(O[3], E[4]); mid[1] = h2max(O[3], E[4]);
    mid[2] = h2min(O[4], E[5]); mid[3] = h2max(O[4], E[5]);
    mid[4] = h2min(O[5], E[6]); mid[5] = h2max(O[5], E[6]);
}

// median(25) = rank-5 (0-idx) of mid6 (sorted) ∪ sorted col5 (verified rounds 2-5).
__device__ __forceinline__ h2 final_medianh(const h2* mid, const h2* c5) {
    const _Float16 hinf = (_Float16)__builtin_inff();
    h2 INF2 = {hinf, hinf};
    h2 Ae[3] = {mid[0], mid[2], mid[4]}, Be[3] = {c5[0], c5[2], c5[4]};
    h2 E[6];
    merge33h(Ae, Be, E);
    h2 Ao[3] = {mid[1], mid[3], mid[5]}, Bo[3] = {c5[1], c5[3], INF2};
    h2 O[6];
    merge33h(Ao, Bo, O);
    return h2min(O[2], E[3]);
}

__global__ __launch_bounds__(256) void median5_kernel(const float* __restrict__ img,
                                                      float* __restrict__ out) {
    const float INF = __builtin_inff();

    if (blockIdx.x < NB_INT) {
        // ===== interior: 8-pixel strips, packed-f16 shared CE network =====
        int gid = blockIdx.x * 256 + threadIdx.x;
        if (gid >= N_STRIPS) return;
        int xs = gid % SPR;
        int t = gid / SPR;
        int y = 2 + t % INT_ROWS;
        int c = t / INT_ROWS;
        int x0 = 2 + 8 * xs;

        const float* p = img + (size_t)c * IMG_H * IMG_W;

        // Packed columns Q[j] = {col_j, col_{j+4}} (rel cols 0..11; abs x0-2..x0+9).
        // Q0={c0,c4} Q1={c1,c5} Q2={c2,c6} Q3={c3,c7} Q4={c4,c8} Q5={c5,c9} Q6={c6,c10} Q7={c7,c11}
        h2 Q[8][5];
#pragma unroll
        for (int r = 0; r < 5; ++r) {
            const float4* rp = (const float4*)(p + (y - 2 + r) * IMG_W + (x0 - 2));
            float4 a = rp[0];   // c0..c3
            float4 b = rp[1];   // c4..c7
            float4 d = rp[2];   // c8..c11
            Q[0][r] = pkrtz(a.x, b.x);
            Q[1][r] = pkrtz(a.y, b.y);
            Q[2][r] = pkrtz(a.z, b.z);
            Q[3][r] = pkrtz(a.w, b.w);
            Q[4][r] = pkrtz(b.x, d.x);
            Q[5][r] = pkrtz(b.y, d.y);
            Q[6][r] = pkrtz(b.z, d.z);
            Q[7][r] = pkrtz(b.w, d.w);
        }
#pragma unroll
        for (int j = 0; j < 8; ++j) sort5h(Q[j]);

        // Packed column-pair merges:
        // MA={M0,M2} MB={M1,M3} MC={M2,M4} MD={M3,M5}  (Mi = merge of col pair (2i,2i+1))
        h2 MA[10], MB[10], MC[10], MD[10];
        merge55h(Q[0], Q[1], MA);
        merge55h(Q[2], Q[3], MB);
        merge55h(Q[4], Q[5], MC);
        merge55h(Q[6], Q[7], MD);

        // Packed mid-merges: midA={mid01,mid23} midB={mid12,mid34} midC={mid23,mid45}
        h2 midA[6], midB[6], midC[6];
        merge1010_midh(MA, MB, midA);
        merge1010_midh(MB, MC, midB);
        merge1010_midh(MC, MD, midC);

        // Packed finals (lo/hi pixel pairs align with direct packed cols):
        // F1={px0,px4} F2={px1,px5} F3={px2,px6} F4={px3,px7}
        h2 F1 = final_medianh(midA, Q[4]);   // (mid01,c4) | (mid23,c8)
        h2 F2 = final_medianh(midB, Q[1]);   // (mid12,c1) | (mid34,c5)
        h2 F3 = final_medianh(midB, Q[6]);   // (mid12,c6) | (mid34,c10)
        h2 F4 = final_medianh(midC, Q[3]);   // (mid23,c3) | (mid45,c7)

        float r0 = (float)F1.x, r4 = (float)F1.y;
        float r1 = (float)F2.x, r5 = (float)F2.y;
        float r2 = (float)F3.x, r6 = (float)F3.y;
        float r3 = (float)F4.x, r7 = (float)F4.y;

        float* po = out + (size_t)c * IMG_H * IMG_W + (size_t)y * IMG_W + x0;
        float2* po2 = (float2*)po;           // 8B aligned
        po2[0] = make_float2(r0, r1);
        po2[1] = make_float2(r2, r3);
        po2[2] = make_float2(r4, r5);
        po2[3] = make_float2(r6, r7);
    } else {
        // ===== boundary frame: exact fp32 bitonic-32 (verified rounds 1-5) =====
        int gid = (blockIdx.x - NB_INT) * 256 + threadIdx.x;
        if (gid >= N_BND) return;
        int c = gid / BND_PER_C;
        int b = gid % BND_PER_C;
        int y, x;
        if (b < 2048) {                 // rows 0,1
            y = b >> 10; x = b & 1023;
        } else if (b < 5120) {          // rows 1021..1023
            int t2 = b - 2048;
            y = 1021 + (t2 >> 10); x = t2 & 1023;
        } else {                        // rows 2..1020, cols {0,1} ∪ {1018..1023}
            int t2 = b - 5120;
            y = 2 + (t2 >> 3);
            int m = t2 & 7;
            x = (m < 2) ? m : (1016 + m);
        }

        const float* p = img + (size_t)c * IMG_H * IMG_W;
        float v[32];
#pragma unroll
        for (int i = 25; i < 32; ++i) v[i] = INF;
#pragma unroll
        for (int dy = -2; dy <= 2; ++dy) {
#pragma unroll
            for (int dx = -2; dx <= 2; ++dx) {
                int yy = y + dy;
                int xx = x + dx;
                bool valid = (yy >= 0) && (yy <= IMG_H - 2) && (xx >= 0) && (xx <= IMG_W - 2);
                int yc = min(max(yy, 0), IMG_H - 1);
                int xc = min(max(xx, 0), IMG_W - 1);
                float val = p[yc * IMG_W + xc];
                v[(dy + 2) * 5 + (dx + 2)] = valid ? val : INF;
            }
        }
#pragma unroll
        for (int k = 2; k <= 32; k <<= 1) {
#pragma unroll
            for (int j = k >> 1; j > 0; j >>= 1) {
#pragma unroll
                for (int i = 0; i < 32; ++i) {
                    int l = i ^ j;
                    if (l > i) {
                        bool up = ((i & k) == 0);
                        float a = v[i];
                        float b2 = v[l];
                        float mn = fminf(a, b2);
                        float mx = fmaxf(a, b2);
                        v[i] = up ? mn : mx;
                        v[l] = up ? mx : mn;
                    }
                }
            }
        }
        int ny = min(y + 2, IMG_H - 2) - max(y - 2, 0) + 1;
        int nx = min(x + 2, IMG_W - 2) - max(x - 2, 0) + 1;
        int n = ny * nx;
        int ilo = (n - 1) >> 1;
        int ihi = n >> 1;
        float lo = 0.0f, hi = 0.0f;
#pragma unroll
        for (int i = 0; i < 13; ++i) {
            if (i == ilo) lo = v[i];
            if (i == ihi) hi = v[i];
        }
        out[(size_t)c * IMG_H * IMG_W + (size_t)y * IMG_W + x] = 0.5f * (lo + hi);
    }
}

extern "C" void kernel_launch(void* const* d_in, const int* in_sizes, int n_in,
                              void* d_out, int out_size, void* d_ws, size_t ws_size,
                              hipStream_t stream) {
    const float* img = (const float*)d_in[0];
    float* out = (float*)d_out;
    dim3 block(256);
    dim3 grid(NB_INT + NB_BND);
    median5_kernel<<<grid, block, 0, stream>>>(img, out);
}

// Round 7
// 67.849 us; speedup vs baseline: 1.0966x; 1.0336x over previous
//
#include <hip/hip_runtime.h>

#define IMG_H 1024
#define IMG_W 1024
#define IMG_C 3

// Interior: x in [2,1017], 8 px wide x 2 rows per thread, 127 strips per row-pair.
#define SPR 127
#define ROWPAIRS 510                            // y0 = min(2+2*rp, 1019); rows y0, y0+1
#define N_STRIPS (IMG_C * ROWPAIRS * SPR)       // 194,310
#define NB_INT ((N_STRIPS + 255) / 256)         // 760
#define INT_ROWS 1019
#define BND_PER_C (5 * 1024 + INT_ROWS * 8)     // 13,272
#define N_BND (IMG_C * BND_PER_C)               // 39,816
#define NB_BND ((N_BND + 255) / 256)            // 156

// ===== packed f16x2 compare-exchange machinery (verified round 6, absmax 0.0078) =====
typedef _Float16 h2 __attribute__((ext_vector_type(2)));

__device__ __forceinline__ h2 h2min(h2 a, h2 b) { return __builtin_elementwise_min(a, b); }
__device__ __forceinline__ h2 h2max(h2 a, h2 b) { return __builtin_elementwise_max(a, b); }
__device__ __forceinline__ void CEh(h2& a, h2& b) { h2 t = h2min(a, b); b = h2max(a, b); a = t; }

__device__ __forceinline__ h2 pkrtz(float a, float b) {
    auto v = __builtin_amdgcn_cvt_pkrtz(a, b);   // v_cvt_pkrtz_f16_f32
    h2 r;
    __builtin_memcpy(&r, &v, sizeof(r));
    return r;
}

__device__ __forceinline__ void merge22h(const h2* A, const h2* B, h2* out) {
    h2 e0 = h2min(A[0], B[0]), e1 = h2max(A[0], B[0]);
    h2 o0 = h2min(A[1], B[1]), o1 = h2max(A[1], B[1]);
    out[0] = e0;
    out[1] = h2min(o0, e1); out[2] = h2max(o0, e1);
    out[3] = o1;
}

__device__ __forceinline__ void merge33h(const h2* A, const h2* B, h2* out) {
    h2 Ae[2] = {A[0], A[2]}, Be[2] = {B[0], B[2]};
    h2 E[4];
    merge22h(Ae, Be, E);
    h2 O0 = h2min(A[1], B[1]), O1 = h2max(A[1], B[1]);
    out[0] = E[0];
    out[1] = h2min(O0, E[1]); out[2] = h2max(O0, E[1]);
    out[3] = h2min(O1, E[2]); out[4] = h2max(O1, E[2]);
    out[5] = E[3];
}

__device__ __forceinline__ void merge55h(const h2* A, const h2* B, h2* out) {
    h2 Ae[3] = {A[0], A[2], A[4]}, Be[3] = {B[0], B[2], B[4]};
    h2 E[6];
    merge33h(Ae, Be, E);
    h2 Ao[2] = {A[1], A[3]}, Bo[2] = {B[1], B[3]};
    h2 O[4];
    merge22h(Ao, Bo, O);
    out[0] = E[0];
    out[1] = h2min(O[0], E[1]); out[2] = h2max(O[0], E[1]);
    out[3] = h2min(O[1], E[2]); out[4] = h2max(O[1], E[2]);
    out[5] = h2min(O[2], E[3]); out[6] = h2max(O[2], E[3]);
    out[7] = h2min(O[3], E[4]); out[8] = h2max(O[3], E[4]);
    out[9] = E[5];
}

__device__ __forceinline__ void merge1010_midh(const h2* A, const h2* B, h2* mid) {
    h2 Ae[5] = {A[0], A[2], A[4], A[6], A[8]}, Be[5] = {B[0], B[2], B[4], B[6], B[8]};
    h2 E[10];
    merge55h(Ae, Be, E);
    h2 Ao[5] = {A[1], A[3], A[5], A[7], A[9]}, Bo[5] = {B[1], B[3], B[5], B[7], B[9]};
    h2 O[10];
    merge55h(Ao, Bo, O);
    mid[0] = h2min(O[3], E[4]); mid[1] = h2max(O[3], E[4]);
    mid[2] = h2min(O[4], E[5]); mid[3] = h2max(O[4], E[5]);
    mid[4] = h2min(O[5], E[6]); mid[5] = h2max(O[5], E[6]);
}

__device__ __forceinline__ h2 final_medianh(const h2* mid, const h2* c5) {
    const _Float16 hinf = (_Float16)__builtin_inff();
    h2 INF2 = {hinf, hinf};
    h2 Ae[3] = {mid[0], mid[2], mid[4]}, Be[3] = {c5[0], c5[2], c5[4]};
    h2 E[6];
    merge33h(Ae, Be, E);
    h2 Ao[3] = {mid[1], mid[3], mid[5]}, Bo[3] = {c5[1], c5[3], INF2};
    h2 O[6];
    merge33h(Ao, Bo, O);
    return h2min(O[2], E[3]);
}

// Whole-strip median network for one window row (verified round 6 structure).
// Q[j] = {col_j, col_{j+4}}, j=0..7 over rel cols 0..11.
__device__ __forceinline__ void strip_medians(const h2 Q[8][5], float* po) {
    h2 MA[10], MB[10], MC[10], MD[10];
    merge55h(Q[0], Q[1], MA);   // {M0, M2}
    merge55h(Q[2], Q[3], MB);   // {M1, M3}
    merge55h(Q[4], Q[5], MC);   // {M2, M4}
    merge55h(Q[6], Q[7], MD);   // {M3, M5}

    h2 midA[6], midB[6], midC[6];
    merge1010_midh(MA, MB, midA);   // {mid01, mid23}
    merge1010_midh(MB, MC, midB);   // {mid12, mid34}
    merge1010_midh(MC, MD, midC);   // {mid23, mid45}

    h2 F1 = final_medianh(midA, Q[4]);   // {px0, px4}
    h2 F2 = final_medianh(midB, Q[1]);   // {px1, px5}
    h2 F3 = final_medianh(midB, Q[6]);   // {px2, px6}
    h2 F4 = final_medianh(midC, Q[3]);   // {px3, px7}

    float2* po2 = (float2*)po;           // 8B aligned
    po2[0] = make_float2((float)F1.x, (float)F2.x);
    po2[1] = make_float2((float)F3.x, (float)F4.x);
    po2[2] = make_float2((float)F1.y, (float)F2.y);
    po2[3] = make_float2((float)F3.y, (float)F4.y);
}

// Insert x into sorted s0<=s1<=s2<=s3 -> sorted out[0..4].
// med3(x,a,b) with a<=b == max(a, min(x,b)) — stays in v_pk_min/max form.
__device__ __forceinline__ void insert5(h2 x, h2 s0, h2 s1, h2 s2, h2 s3, h2* out) {
    out[0] = h2min(x, s0);
    out[1] = h2max(s0, h2min(x, s1));
    out[2] = h2max(s1, h2min(x, s2));
    out[3] = h2max(s2, h2min(x, s3));
    out[4] = h2max(x, s3);
}

__global__ __launch_bounds__(256) void median5_kernel(const float* __restrict__ img,
                                                      float* __restrict__ out) {
    const float INF = __builtin_inff();

    if (blockIdx.x >= NB_BND) {
        // ===== interior: 8x2 strips, shared vertical sort + packed-f16 network =====
        int gid = (blockIdx.x - NB_BND) * 256 + threadIdx.x;
        if (gid >= N_STRIPS) return;
        int xs = gid % SPR;
        int t = gid / SPR;
        int rp = t % ROWPAIRS;
        int c = t / ROWPAIRS;
        int y0 = 2 + 2 * rp;
        if (y0 > 1019) y0 = 1019;       // last pair overlaps: rows 1019,1020 (1019 recomputed, same value)
        int x0 = 2 + 8 * xs;

        const float* p = img + (size_t)c * IMG_H * IMG_W;

        // V[j][r] packed {col_j, col_{j+4}} over 6 rows y0-2 .. y0+3.
        h2 V[8][6];
#pragma unroll
        for (int r = 0; r < 6; ++r) {
            const float4* rpnt = (const float4*)(p + (y0 - 2 + r) * IMG_W + (x0 - 2));
            float4 a = rpnt[0];   // c0..c3
            float4 b = rpnt[1];   // c4..c7
            float4 d = rpnt[2];   // c8..c11
            V[0][r] = pkrtz(a.x, b.x);
            V[1][r] = pkrtz(a.y, b.y);
            V[2][r] = pkrtz(a.z, b.z);
            V[3][r] = pkrtz(a.w, b.w);
            V[4][r] = pkrtz(b.x, d.x);
            V[5][r] = pkrtz(b.y, d.y);
            V[6][r] = pkrtz(b.z, d.z);
            V[7][r] = pkrtz(b.w, d.w);
        }

        // Shared middle sort: V[j][1..4] -> ascending (5-CE 4-sorter).
#pragma unroll
        for (int j = 0; j < 8; ++j) {
            CEh(V[j][1], V[j][2]); CEh(V[j][3], V[j][4]);
            CEh(V[j][1], V[j][3]); CEh(V[j][2], V[j][4]);
            CEh(V[j][2], V[j][3]);
        }

        float* po = out + (size_t)c * IMG_H * IMG_W + (size_t)y0 * IMG_W + x0;

        // Window A: rows y0-2..y0+2 (insert V[j][0]).
        {
            h2 QA[8][5];
#pragma unroll
            for (int j = 0; j < 8; ++j)
                insert5(V[j][0], V[j][1], V[j][2], V[j][3], V[j][4], QA[j]);
            strip_medians(QA, po);
        }
        // Window B: rows y0-1..y0+3 (insert V[j][5]).
        {
            h2 QB[8][5];
#pragma unroll
            for (int j = 0; j < 8; ++j)
                insert5(V[j][5], V[j][1], V[j][2], V[j][3], V[j][4], QB[j]);
            strip_medians(QB, po + IMG_W);
        }
    } else {
        // ===== boundary frame FIRST (no tail): exact fp32 bitonic-32 (verified) =====
        int gid = blockIdx.x * 256 + threadIdx.x;
        if (gid >= N_BND) return;
        int c = gid / BND_PER_C;
        int b = gid % BND_PER_C;
        int y, x;
        if (b < 2048) {                 // rows 0,1
            y = b >> 10; x = b & 1023;
        } else if (b < 5120) {          // rows 1021..1023
            int t2 = b - 2048;
            y = 1021 + (t2 >> 10); x = t2 & 1023;
        } else {                        // rows 2..1020, cols {0,1} ∪ {1018..1023}
            int t2 = b - 5120;
            y = 2 + (t2 >> 3);
            int m = t2 & 7;
            x = (m < 2) ? m : (1016 + m);
        }

        const float* p = img + (size_t)c * IMG_H * IMG_W;
        float v[32];
#pragma unroll
        for (int i = 25; i < 32; ++i) v[i] = INF;
#pragma unroll
        for (int dy = -2; dy <= 2; ++dy) {
#pragma unroll
            for (int dx = -2; dx <= 2; ++dx) {
                int yy = y + dy;
                int xx = x + dx;
                bool valid = (yy >= 0) && (yy <= IMG_H - 2) && (xx >= 0) && (xx <= IMG_W - 2);
                int yc = min(max(yy, 0), IMG_H - 1);
                int xc = min(max(xx, 0), IMG_W - 1);
                float val = p[yc * IMG_W + xc];
                v[(dy + 2) * 5 + (dx + 2)] = valid ? val : INF;
            }
        }
#pragma unroll
        for (int k = 2; k <= 32; k <<= 1) {
#pragma unroll
            for (int j = k >> 1; j > 0; j >>= 1) {
#pragma unroll
                for (int i = 0; i < 32; ++i) {
                    int l = i ^ j;
                    if (l > i) {
                        bool up = ((i & k) == 0);
                        float a = v[i];
                        float b2 = v[l];
                        float mn = fminf(a, b2);
                        float mx = fmaxf(a, b2);
                        v[i] = up ? mn : mx;
                        v[l] = up ? mx : mn;
                    }
                }
            }
        }
        int ny = min(y + 2, IMG_H - 2) - max(y - 2, 0) + 1;
        int nx = min(x + 2, IMG_W - 2) - max(x - 2, 0) + 1;
        int n = ny * nx;
        int ilo = (n - 1) >> 1;
        int ihi = n >> 1;
        float lo = 0.0f, hi = 0.0f;
#pragma unroll
        for (int i = 0; i < 13; ++i) {
            if (i == ilo) lo = v[i];
            if (i == ihi) hi = v[i];
        }
        out[(size_t)c * IMG_H * IMG_W + (size_t)y * IMG_W + x] = 0.5f * (lo + hi);
    }
}

extern "C" void kernel_launch(void* const* d_in, const int* in_sizes, int n_in,
                              void* d_out, int out_size, void* d_ws, size_t ws_size,
                              hipStream_t stream) {
    const float* img = (const float*)d_in[0];
    float* out = (float*)d_out;
    dim3 block(256);
    dim3 grid(NB_BND + NB_INT);
    median5_kernel<<<grid, block, 0, stream>>>(img, out);
}